// Round 1
// baseline (481.010 us; speedup 1.0000x reference)
//
#include <hip/hip_runtime.h>
#include <hip/hip_bf16.h>
#include <math.h>

// Problem constants (from reference setup_inputs):
//   B=4, N_UP=8192, N_SEED=2048 (unused), N_GT=8192, N_RAD=1024
// Inputs: d_in[0]=pc_up [4,8192,3] f32, d_in[1]=pc_seed (unused),
//         d_in[2]=pc_conf [4,1024,1] f32, d_in[3]=pc2 [4,8192,3] f32,
//         d_in[4]=pc3 [4,1024,3] f32.
// Output: scalar f32 loss.
//
// final = 0.25*mean(dist1) + 1.0*mean(dist2) + 0.5*mean((conf-exp(-sqrt(d_rad)))^2)
//         + mean(sqrt(dist1))

#define TS 512  // LDS tile of B-points per iteration

__global__ void init_ws_kernel(unsigned int* ws, int n) {
    int i = blockIdx.x * blockDim.x + threadIdx.x;
    if (i < n) ws[i] = 0x7F800000u;  // +inf bits
}

// Generic row-min pass: for each row point a in Apts, compute
// min over a column chunk of Bpts of ||a-b||^2, combine via atomicMin.
// Apts: [Bb, NA, 3] flat; Bpts: [Bb, NB, 3] flat; outmin: [Bb*NA] (uint +inf init)
// grid.x = Bb*NA/256 (row blocks), grid.y = NB/colsPerBlock (column splits)
__global__ void row_min_kernel(const float* __restrict__ Apts,
                               const float* __restrict__ Bpts,
                               float* __restrict__ outmin,
                               int NA, int NB, int colsPerBlock) {
    __shared__ float4 tile[TS];  // (x, y, z, x^2+y^2+z^2)

    const int row = blockIdx.x * 256 + threadIdx.x;   // global row (batch-major)
    const int b   = row / NA;
    const float ax = Apts[row * 3 + 0];
    const float ay = Apts[row * 3 + 1];
    const float az = Apts[row * 3 + 2];
    const float a2 = ax * ax + ay * ay + az * az;

    const float* Bbase = Bpts + (size_t)b * NB * 3 + (size_t)blockIdx.y * colsPerBlock * 3;

    float m = INFINITY;  // min over j of (b2_j - 2*a.b_j)

    for (int t0 = 0; t0 < colsPerBlock; t0 += TS) {
        __syncthreads();  // protect tile from previous iteration's readers
        const float* src = Bbase + (size_t)t0 * 3;
        for (int k = threadIdx.x; k < TS; k += 256) {
            float x = src[k * 3 + 0];
            float y = src[k * 3 + 1];
            float z = src[k * 3 + 2];
            tile[k] = make_float4(x, y, z, x * x + y * y + z * z);
        }
        __syncthreads();

#pragma unroll 8
        for (int j = 0; j < TS; ++j) {
            float4 p = tile[j];  // uniform-address ds_read_b128 (broadcast)
            float ab = fmaf(ax, p.x, fmaf(ay, p.y, az * p.z));
            float t  = fmaf(-2.0f, ab, p.w);  // b2 - 2ab
            m = fminf(m, t);
        }
    }

    // d = max(a2 + min(b2-2ab), 0) == min over clamped pair distances
    float d = fmaxf(a2 + m, 0.0f);
    atomicMin((unsigned int*)&outmin[row], __float_as_uint(d));
}

__global__ void reduce_kernel(const float* __restrict__ ws1,   // dist1 [32768]
                              const float* __restrict__ ws2,   // dist2 [32768]
                              const float* __restrict__ ws3,   // d_rad_min [4096]
                              const float* __restrict__ conf,  // [4096]
                              float* __restrict__ out) {
    float s_d1 = 0.f, s_sq1 = 0.f, s_d2 = 0.f, s_conf = 0.f;

    for (int k = threadIdx.x; k < 32768; k += 256) {
        float v = ws1[k];
        s_d1  += v;
        s_sq1 += sqrtf(v);
        float w = ws2[k];
        s_d2  += w;
    }
    for (int k = threadIdx.x; k < 4096; k += 256) {
        float v = ws3[k];
        float score = expf(-sqrtf(v));
        float diff  = conf[k] - score;
        s_conf += diff * diff;
    }

    // block reduction of 4 sums: wave shuffle then cross-wave via LDS
    __shared__ float wsum[4][4];  // [wave][quantity]
    const int lane = threadIdx.x & 63;
    const int wave = threadIdx.x >> 6;
    float vals[4] = {s_d1, s_sq1, s_d2, s_conf};
#pragma unroll
    for (int q = 0; q < 4; ++q) {
        float v = vals[q];
        for (int off = 32; off > 0; off >>= 1) v += __shfl_down(v, off, 64);
        if (lane == 0) wsum[wave][q] = v;
    }
    __syncthreads();
    if (threadIdx.x == 0) {
        float t[4] = {0.f, 0.f, 0.f, 0.f};
        for (int w = 0; w < 4; ++w)
            for (int q = 0; q < 4; ++q) t[q] += wsum[w][q];
        // t[0]=sum dist1, t[1]=sum sqrt(dist1), t[2]=sum dist2, t[3]=sum conf sq err
        out[0] = 0.25f * (t[0] / 32768.f)
               + (t[2] / 32768.f)
               + 0.5f * (t[3] / 4096.f)
               + (t[1] / 32768.f);
    }
}

extern "C" void kernel_launch(void* const* d_in, const int* in_sizes, int n_in,
                              void* d_out, int out_size, void* d_ws, size_t ws_size,
                              hipStream_t stream) {
    const float* pc_up   = (const float*)d_in[0];
    const float* pc_conf = (const float*)d_in[2];
    const float* pc2     = (const float*)d_in[3];
    const float* pc3     = (const float*)d_in[4];

    float* ws1 = (float*)d_ws;        // [32768] dist1 (up->gt min)
    float* ws2 = ws1 + 32768;         // [32768] dist2 (gt->up min)
    float* ws3 = ws2 + 32768;         // [4096]  radar->gt min
    const int n_ws = 32768 + 32768 + 4096;

    init_ws_kernel<<<(n_ws + 255) / 256, 256, 0, stream>>>((unsigned int*)d_ws, n_ws);

    // Pass A: dist1 rows=pc_up (4*8192), cols=pc2 (8192/batch), 4-way col split
    row_min_kernel<<<dim3(128, 4), 256, 0, stream>>>(pc_up, pc2, ws1, 8192, 8192, 2048);
    // Pass B: dist2 rows=pc2, cols=pc_up
    row_min_kernel<<<dim3(128, 4), 256, 0, stream>>>(pc2, pc_up, ws2, 8192, 8192, 2048);
    // Pass C: radar rows=pc3 (4*1024), cols=pc2, 8-way col split
    row_min_kernel<<<dim3(16, 8), 256, 0, stream>>>(pc3, pc2, ws3, 1024, 8192, 1024);

    reduce_kernel<<<1, 256, 0, stream>>>(ws1, ws2, ws3, pc_conf, (float*)d_out);
}

// Round 2
// 106.287 us; speedup vs baseline: 4.5256x; 4.5256x over previous
//
#include <hip/hip_runtime.h>
#include <hip/hip_bf16.h>
#include <math.h>

// Problem: B=4, N_UP=8192, N_GT=8192, N_RAD=1024 (N_SEED unused)
// final = 0.25*mean(dist1) + mean(dist2) + 0.5*mean((conf-exp(-sqrt(d_rad)))^2)
//         + mean(sqrt(dist1))
//
// Strategy: register-tiled row-min passes. Each thread owns R rows in VGPRs;
// B-points staged in LDS as (-2x,-2y,-2z,b^2) so per pair = 3 fma + 0.5 min3.
// All three passes fused into one launch (1280 blocks); column splits combined
// via atomicMin on float-as-uint (valid: all distances >= 0).

#define THREADS 256

__global__ void init_ws_kernel(unsigned int* ws, float* out) {
    int i = blockIdx.x * THREADS + threadIdx.x;
    if (i == 0) out[0] = 0.0f;
    if (i < 69632) ws[i] = 0x7F800000u;  // +inf bits
}

// One (row-block, col-split) chunk: rows rowBase..rowBase+256*R-1 (whole chunk
// inside one batch by construction), cols sp*COLS..sp*COLS+COLS-1 of that batch.
template <int R, int COLS>
__device__ void row_min_body(const float* __restrict__ A,
                             const float* __restrict__ Bp,
                             float* __restrict__ outmin,
                             int NA, int NB, int rb, int sp) {
    __shared__ float4 tile[COLS];  // (-2x, -2y, -2z, x^2+y^2+z^2)

    const int rowBase = rb * (THREADS * R);
    const int b = rowBase / NA;

    const float* src = Bp + (size_t)(b * NB + sp * COLS) * 3;
    for (int k = threadIdx.x; k < COLS; k += THREADS) {
        float x = src[k * 3 + 0];
        float y = src[k * 3 + 1];
        float z = src[k * 3 + 2];
        tile[k] = make_float4(-2.0f * x, -2.0f * y, -2.0f * z,
                              x * x + y * y + z * z);
    }

    float ax[R], ay[R], az[R], m[R];
#pragma unroll
    for (int r = 0; r < R; ++r) {
        int row = rowBase + r * THREADS + threadIdx.x;
        ax[r] = A[row * 3 + 0];
        ay[r] = A[row * 3 + 1];
        az[r] = A[row * 3 + 2];
        m[r] = INFINITY;
    }
    __syncthreads();

#pragma unroll 4
    for (int j = 0; j < COLS; j += 2) {
        float4 p = tile[j];      // uniform-address broadcast ds_read_b128
        float4 q = tile[j + 1];
#pragma unroll
        for (int r = 0; r < R; ++r) {
            float t0 = fmaf(ax[r], p.x, fmaf(ay[r], p.y, fmaf(az[r], p.z, p.w)));
            float t1 = fmaf(ax[r], q.x, fmaf(ay[r], q.y, fmaf(az[r], q.z, q.w)));
            m[r] = fminf(m[r], fminf(t0, t1));  // folds to v_min3_f32
        }
    }

#pragma unroll
    for (int r = 0; r < R; ++r) {
        int row = rowBase + r * THREADS + threadIdx.x;
        float a2 = fmaf(ax[r], ax[r], fmaf(ay[r], ay[r], az[r] * az[r]));
        float d = fmaxf(a2 + m[r], 0.0f);  // min/clamp commute (max monotone)
        atomicMin((unsigned int*)&outmin[row], __float_as_uint(d));
    }
}

// Fused: blocks [0,512) pass A (up->gt), [512,1024) pass B (gt->up),
// [1024,1280) pass C (radar->gt).
__global__ __launch_bounds__(THREADS, 2) void
pass_kernel(const float* __restrict__ pc_up, const float* __restrict__ pc2,
            const float* __restrict__ pc3, float* ws1, float* ws2, float* ws3) {
    int bid = blockIdx.x;
    if (bid < 512) {
        // A: rows=pc_up (8 row-blocks of 4096), 64 col-splits of 128
        row_min_body<16, 128>(pc_up, pc2, ws1, 8192, 8192, bid >> 6, bid & 63);
    } else if (bid < 1024) {
        bid -= 512;
        row_min_body<16, 128>(pc2, pc_up, ws2, 8192, 8192, bid >> 6, bid & 63);
    } else {
        bid -= 1024;
        // C: rows=pc3 (4 row-blocks of 1024 = one batch each), 64 splits
        row_min_body<4, 128>(pc3, pc2, ws3, 1024, 8192, bid >> 6, bid & 63);
    }
}

#define RED_BLOCKS 64

__global__ void reduce_kernel(const float* __restrict__ ws1,
                              const float* __restrict__ ws2,
                              const float* __restrict__ ws3,
                              const float* __restrict__ conf,
                              float* __restrict__ out) {
    const int gid = blockIdx.x * THREADS + threadIdx.x;
    const int stride = RED_BLOCKS * THREADS;

    float s = 0.0f;
    const float w1 = 0.25f / 32768.0f;   // 0.5*ALPHA * mean(dist1)
    const float wq = 1.0f / 32768.0f;    // mean(sqrt(dist1))  [emd]
    const float w2 = 1.0f / 32768.0f;    // 2*ALPHA*0.5... = 1.0 * mean(dist2)
    const float w3 = 0.5f / 4096.0f;     // ALPHA * mean conf sq err

    for (int k = gid; k < 32768; k += stride) {
        float v = ws1[k];
        s += w1 * v + wq * sqrtf(v);
        s += w2 * ws2[k];
    }
    for (int k = gid; k < 4096; k += stride) {
        float v = ws3[k];
        float diff = conf[k] - expf(-sqrtf(v));
        s += w3 * diff * diff;
    }

    // block reduction
    __shared__ float wsum[4];
    const int lane = threadIdx.x & 63;
    const int wave = threadIdx.x >> 6;
    for (int off = 32; off > 0; off >>= 1) s += __shfl_down(s, off, 64);
    if (lane == 0) wsum[wave] = s;
    __syncthreads();
    if (threadIdx.x == 0) {
        float t = wsum[0] + wsum[1] + wsum[2] + wsum[3];
        atomicAdd(out, t);
    }
}

extern "C" void kernel_launch(void* const* d_in, const int* in_sizes, int n_in,
                              void* d_out, int out_size, void* d_ws, size_t ws_size,
                              hipStream_t stream) {
    const float* pc_up   = (const float*)d_in[0];
    const float* pc_conf = (const float*)d_in[2];
    const float* pc2     = (const float*)d_in[3];
    const float* pc3     = (const float*)d_in[4];

    float* ws1 = (float*)d_ws;   // [32768] dist1 (up->gt min)
    float* ws2 = ws1 + 32768;    // [32768] dist2 (gt->up min)
    float* ws3 = ws2 + 32768;    // [4096]  radar->gt min

    init_ws_kernel<<<272, THREADS, 0, stream>>>((unsigned int*)d_ws, (float*)d_out);
    pass_kernel<<<1280, THREADS, 0, stream>>>(pc_up, pc2, pc3, ws1, ws2, ws3);
    reduce_kernel<<<RED_BLOCKS, THREADS, 0, stream>>>(ws1, ws2, ws3, pc_conf,
                                                      (float*)d_out);
}